// Round 4
// baseline (1164.652 us; speedup 1.0000x reference)
//
#include <hip/hip_runtime.h>
#include <hip/hip_bf16.h>

typedef __bf16 bf16x8 __attribute__((ext_vector_type(8)));
typedef float f32x4 __attribute__((ext_vector_type(4)));
typedef unsigned short u16;
typedef u16 u16x4 __attribute__((ext_vector_type(4)));

__device__ __forceinline__ u16 bfbits(float f) {
  return __builtin_bit_cast(u16, (__bf16)f);
}

// ---------------- prep: weights -> bf16, bias gather [h][query][key] ----------------
__global__ void wattn_prep(const float* __restrict__ wq, const float* __restrict__ wp,
                           const float* __restrict__ rpb, const int* __restrict__ rpi,
                           u16* __restrict__ wqb, u16* __restrict__ wpb,
                           float* __restrict__ biasb) {
  int i = blockIdx.x * blockDim.x + threadIdx.x;      // 196608 threads
  if (i < 196608) wqb[i] = bfbits(wq[i]);             // w_qkv [768][256]
  if (i < 65536)  wpb[i] = bfbits(wp[i]);             // w_proj [256][256]
  if (i < 32768) {                                    // bias [8][query 64][key 64]
    int h = i >> 12, nm = i & 4095;
    biasb[i] = rpb[rpi[nm] * 8 + h];
  }
}

// ---------------- fused window attention ----------------
// block = 1 window, 512 threads = 8 waves, wave w = head w
// LDS: Xb [64][264] bf16 only (aliased as attn_out for proj). 33792 B -> 3-4 blocks/CU.
// Q, K, V, P all stay in registers: transposed Q/K GEMM + non-transposed V GEMM;
// MFMA C-fragments are re-fed as A/B operands via the k-slot permutation
// pi(g,j) = j<4 ? 4g+j : 16+4g+(j-4), applied consistently to both operands.
__global__ __launch_bounds__(512, 6)
void wattn_main(const float* __restrict__ x,
                const u16* __restrict__ wq, const float* __restrict__ bq,
                const u16* __restrict__ wp, const float* __restrict__ bp,
                const float* __restrict__ bias,
                float* __restrict__ out) {
  extern __shared__ u16 sm[];
  u16* Xb = sm;                       // 64*264 = 16896 u16 = 33792 B

  const int b    = blockIdx.x;
  const int tid  = threadIdx.x;
  const int w    = tid >> 6;          // wave = head
  const int lane = tid & 63;
  const int g    = lane >> 4;
  const int li   = lane & 15;
  const int hc   = 32 * w;

  // ---- stage x -> bf16 LDS ----
  {
    const float4* xg = (const float4*)(x + (size_t)b * 16384);
    #pragma unroll
    for (int i = 0; i < 8; ++i) {
      int idx = tid + i * 512;
      float4 v = xg[idx];
      int n = idx >> 6, c = (idx & 63) * 4;
      u16x4 h;
      h[0] = bfbits(v.x); h[1] = bfbits(v.y); h[2] = bfbits(v.z); h[3] = bfbits(v.w);
      *(u16x4*)(Xb + n * 264 + c) = h;
    }
  }
  __syncthreads();

  const int xoff = li * 264 + 8 * g;        // per-lane Xb fragment base
  const float scale = 0.17677669529663687f; // 1/sqrt(32)

  // ======== Q sweep: Q^T = Wq . x^T -> qf fragments (B-operand of S-mfma) ========
  bf16x8 qf[4];
  {
    f32x4 aq[2][4];
    #pragma unroll
    for (int mt = 0; mt < 2; ++mt)
      #pragma unroll
      for (int nt = 0; nt < 4; ++nt) aq[mt][nt] = f32x4{0,0,0,0};
    #pragma unroll 2
    for (int ks = 0; ks < 8; ++ks) {
      bf16x8 xb[4];
      #pragma unroll
      for (int nt = 0; nt < 4; ++nt)
        xb[nt] = *(const bf16x8*)(Xb + xoff + nt * (16 * 264) + 32 * ks);
      #pragma unroll
      for (int mt = 0; mt < 2; ++mt) {
        bf16x8 wf = *(const bf16x8*)(wq + (hc + 16 * mt + li) * 256 + 32 * ks + 8 * g);
        #pragma unroll
        for (int nt = 0; nt < 4; ++nt)
          aq[mt][nt] = __builtin_amdgcn_mfma_f32_16x16x32_bf16(wf, xb[nt], aq[mt][nt], 0, 0, 0);
      }
    }
    #pragma unroll
    for (int j = 0; j < 8; ++j) {
      int d = (j < 4) ? (4 * g + j) : (16 + 4 * g + (j - 4));
      float bb = bq[hc + d];
      #pragma unroll
      for (int t = 0; t < 4; ++t)
        qf[t][j] = (__bf16)(((j < 4 ? aq[0][t][j] : aq[1][t][j - 4]) + bb) * scale);
    }
  }
  __builtin_amdgcn_sched_barrier(0);

  // ======== K sweep: K^T = Wk . x^T -> kf fragments (A-operand of S-mfma) ========
  bf16x8 kf[4];
  {
    f32x4 ak[2][4];
    #pragma unroll
    for (int mt = 0; mt < 2; ++mt)
      #pragma unroll
      for (int nt = 0; nt < 4; ++nt) ak[mt][nt] = f32x4{0,0,0,0};
    #pragma unroll 2
    for (int ks = 0; ks < 8; ++ks) {
      bf16x8 xb[4];
      #pragma unroll
      for (int nt = 0; nt < 4; ++nt)
        xb[nt] = *(const bf16x8*)(Xb + xoff + nt * (16 * 264) + 32 * ks);
      #pragma unroll
      for (int mt = 0; mt < 2; ++mt) {
        bf16x8 wf = *(const bf16x8*)(wq + (256 + hc + 16 * mt + li) * 256 + 32 * ks + 8 * g);
        #pragma unroll
        for (int nt = 0; nt < 4; ++nt)
          ak[mt][nt] = __builtin_amdgcn_mfma_f32_16x16x32_bf16(wf, xb[nt], ak[mt][nt], 0, 0, 0);
      }
    }
    #pragma unroll
    for (int j = 0; j < 8; ++j) {
      int d = (j < 4) ? (4 * g + j) : (16 + 4 * g + (j - 4));
      float bb = bq[256 + hc + d];
      #pragma unroll
      for (int t = 0; t < 4; ++t)
        kf[t][j] = (__bf16)((j < 4 ? ak[0][t][j] : ak[1][t][j - 4]) + bb);
    }
  }
  __builtin_amdgcn_sched_barrier(0);

  // ======== V sweep (non-transposed): V = x . Wv^T -> vb fragments (B-operand of PV) ========
  // av[mt][nt]: C row = token 16mt+4g+e, col = d = 16nt+li
  bf16x8 vb[2][2];
  {
    f32x4 av[4][2];
    #pragma unroll
    for (int mt = 0; mt < 4; ++mt)
      #pragma unroll
      for (int nt = 0; nt < 2; ++nt) av[mt][nt] = f32x4{0,0,0,0};
    #pragma unroll 2
    for (int ks = 0; ks < 8; ++ks) {
      bf16x8 xb[4];
      #pragma unroll
      for (int mt = 0; mt < 4; ++mt)
        xb[mt] = *(const bf16x8*)(Xb + xoff + mt * (16 * 264) + 32 * ks);
      #pragma unroll
      for (int nt = 0; nt < 2; ++nt) {
        bf16x8 wf = *(const bf16x8*)(wq + (512 + hc + 16 * nt + li) * 256 + 32 * ks + 8 * g);
        #pragma unroll
        for (int mt = 0; mt < 4; ++mt)
          av[mt][nt] = __builtin_amdgcn_mfma_f32_16x16x32_bf16(xb[mt], wf, av[mt][nt], 0, 0, 0);
      }
    }
    // C-frag -> PV B-frag via pi: vb[kk][nt][j] = V[token 32kk+pi(g,j)][d 16nt+li]
    #pragma unroll
    for (int nt = 0; nt < 2; ++nt) {
      float bb = bq[512 + hc + 16 * nt + li];
      #pragma unroll
      for (int kk = 0; kk < 2; ++kk)
        #pragma unroll
        for (int j = 0; j < 8; ++j)
          vb[kk][nt][j] = (__bf16)((j < 4 ? av[2 * kk][nt][j] : av[2 * kk + 1][nt][j - 4]) + bb);
    }
  }
  __builtin_amdgcn_sched_barrier(0);

  // ======== S^T = K.Q^T per query-tile; bias + softmax over keys; P fragments ========
  bf16x8 pa[4][2];
  {
    const float* bh = bias + w * 4096;      // [query][key]
    #pragma unroll
    for (int ct = 0; ct < 4; ++ct) {
      f32x4 s4[4];
      #pragma unroll
      for (int rt = 0; rt < 4; ++rt)
        s4[rt] = __builtin_amdgcn_mfma_f32_16x16x32_bf16(kf[rt], qf[ct], f32x4{0,0,0,0}, 0, 0, 0);
      const float* bq_row = bh + (16 * ct + li) * 64 + 4 * g;
      float mx = -1e30f;
      #pragma unroll
      for (int rt = 0; rt < 4; ++rt) {
        f32x4 bv = *(const f32x4*)(bq_row + 16 * rt);
        #pragma unroll
        for (int e = 0; e < 4; ++e) {
          s4[rt][e] += bv[e];
          mx = fmaxf(mx, s4[rt][e]);
        }
      }
      mx = fmaxf(mx, __shfl_xor(mx, 16));
      mx = fmaxf(mx, __shfl_xor(mx, 32));
      float sum = 0.f;
      #pragma unroll
      for (int rt = 0; rt < 4; ++rt)
        #pragma unroll
        for (int e = 0; e < 4; ++e) {
          float p = __expf(s4[rt][e] - mx);
          s4[rt][e] = p;
          sum += p;
        }
      sum += __shfl_xor(sum, 16);
      sum += __shfl_xor(sum, 32);
      float rs = 1.0f / sum;
      #pragma unroll
      for (int kk = 0; kk < 2; ++kk)
        #pragma unroll
        for (int j = 0; j < 8; ++j)
          pa[ct][kk][j] = (__bf16)((j < 4 ? s4[2 * kk][j] : s4[2 * kk + 1][j - 4]) * rs);
    }
  }
  __builtin_amdgcn_sched_barrier(0);

  // ======== O = P.V entirely in-register ========
  f32x4 o[4][2];
  #pragma unroll
  for (int mt = 0; mt < 4; ++mt)
    #pragma unroll
    for (int nt = 0; nt < 2; ++nt) o[mt][nt] = f32x4{0,0,0,0};
  #pragma unroll
  for (int kk = 0; kk < 2; ++kk)
    #pragma unroll
    for (int mt = 0; mt < 4; ++mt)
      #pragma unroll
      for (int nt = 0; nt < 2; ++nt)
        o[mt][nt] = __builtin_amdgcn_mfma_f32_16x16x32_bf16(pa[mt][kk], vb[kk][nt], o[mt][nt], 0, 0, 0);

  // ======== attn_out -> LDS (aliases Xb; Xb dead after V sweep) ========
  __syncthreads();
  u16* ao = sm;                       // [64][264]
  #pragma unroll
  for (int mt = 0; mt < 4; ++mt)
    #pragma unroll
    for (int nt = 0; nt < 2; ++nt)
      #pragma unroll
      for (int e = 0; e < 4; ++e)
        ao[(16 * mt + 4 * g + e) * 264 + hc + 16 * nt + li] = bfbits(o[mt][nt][e]);
  __syncthreads();

  // ======== proj: out = attn_out @ Wp^T + bp ; wave w -> cols 32w..32w+31 ========
  f32x4 c2[4][2];
  #pragma unroll
  for (int rt = 0; rt < 4; ++rt)
    #pragma unroll
    for (int ct = 0; ct < 2; ++ct) c2[rt][ct] = f32x4{0,0,0,0};
  #pragma unroll 2
  for (int ks = 0; ks < 8; ++ks) {
    bf16x8 af[4];
    #pragma unroll
    for (int rt = 0; rt < 4; ++rt)
      af[rt] = *(const bf16x8*)(ao + xoff + rt * (16 * 264) + 32 * ks);
    bf16x8 wf[2];
    #pragma unroll
    for (int ct = 0; ct < 2; ++ct)
      wf[ct] = *(const bf16x8*)(wp + (32 * w + 16 * ct + li) * 256 + 32 * ks + 8 * g);
    #pragma unroll
    for (int rt = 0; rt < 4; ++rt)
      #pragma unroll
      for (int ct = 0; ct < 2; ++ct)
        c2[rt][ct] = __builtin_amdgcn_mfma_f32_16x16x32_bf16(af[rt], wf[ct], c2[rt][ct], 0, 0, 0);
  }
  {
    float* og = out + (size_t)b * 16384;
    #pragma unroll
    for (int ct = 0; ct < 2; ++ct) {
      int col = 32 * w + 16 * ct + li;
      float bpv = bp[col];
      #pragma unroll
      for (int rt = 0; rt < 4; ++rt)
        #pragma unroll
        for (int e = 0; e < 4; ++e)
          og[(16 * rt + 4 * g + e) * 256 + col] = c2[rt][ct][e] + bpv;
    }
  }
}

extern "C" void kernel_launch(void* const* d_in, const int* in_sizes, int n_in,
                              void* d_out, int out_size, void* d_ws, size_t ws_size,
                              hipStream_t stream) {
  const float* x   = (const float*)d_in[0];
  const float* wqv = (const float*)d_in[1];
  const float* bq  = (const float*)d_in[2];
  const float* wpr = (const float*)d_in[3];
  const float* bp  = (const float*)d_in[4];
  const float* rpb = (const float*)d_in[5];
  const int*   rpi = (const int*)d_in[6];
  float* out = (float*)d_out;

  u16*   wqb   = (u16*)d_ws;            // 196608 bf16
  u16*   wpb   = wqb + 196608;          // 65536 bf16
  float* biasb = (float*)(wpb + 65536); // 32768 f32 ([h][query][key])

  wattn_prep<<<384, 512, 0, stream>>>(wqv, wpr, rpb, rpi, wqb, wpb, biasb);

  const size_t smem = 16896 * sizeof(u16);  // 33792 B
  hipFuncSetAttribute(reinterpret_cast<const void*>(wattn_main),
                      hipFuncAttributeMaxDynamicSharedMemorySize, (int)smem);
  wattn_main<<<8192, 512, smem, stream>>>(x, wqb, bq, wpb, bp, biasb, out);
}

// Round 6
// 760.229 us; speedup vs baseline: 1.5320x; 1.5320x over previous
//
#include <hip/hip_runtime.h>
#include <hip/hip_bf16.h>

typedef __bf16 bf16x8 __attribute__((ext_vector_type(8)));
typedef float f32x4 __attribute__((ext_vector_type(4)));
typedef unsigned short u16;
typedef u16 u16x4 __attribute__((ext_vector_type(4)));

__device__ __forceinline__ u16 bfbits(float f) {
  return __builtin_bit_cast(u16, (__bf16)f);
}

// ---------------- prep: weights -> bf16, bias gather [h][query][key] ----------------
__global__ void wattn_prep(const float* __restrict__ wq, const float* __restrict__ wp,
                           const float* __restrict__ rpb, const int* __restrict__ rpi,
                           u16* __restrict__ wqb, u16* __restrict__ wpb,
                           float* __restrict__ biasb) {
  int i = blockIdx.x * blockDim.x + threadIdx.x;      // 196608 threads
  if (i < 196608) wqb[i] = bfbits(wq[i]);             // w_qkv [768][256]
  if (i < 65536)  wpb[i] = bfbits(wp[i]);             // w_proj [256][256]
  if (i < 32768) {                                    // bias [8][query 64][key 64]
    int h = i >> 12, nm = i & 4095;
    biasb[i] = rpb[rpi[nm] * 8 + h];
  }
}

// ---------------- fused window attention ----------------
// block = 1 window, 512 threads = 8 waves, wave w = head w
// LDS: Xb [64][264] bf16 | Ao [64][264] bf16 (SEPARATE — R5's Ao-aliases-Xb caused a
// timing-dependent race at cap-128 scheduling; post-timing divergence 1.35e-2).
// Q, K, V, P all stay in registers: transposed Q/K GEMM + non-transposed V GEMM;
// MFMA C-fragments are re-fed as A/B operands via the k-slot permutation
// pi(g,j) = j<4 ? 4g+j : 16+4g+(j-4), applied consistently to both operands.
// launch_bounds (512,4): VGPR cap 128 — cap 85 spills ~2 GB scratch (R4).
__global__ __launch_bounds__(512, 4)
void wattn_main(const float* __restrict__ x,
                const u16* __restrict__ wq, const float* __restrict__ bq,
                const u16* __restrict__ wp, const float* __restrict__ bp,
                const float* __restrict__ bias,
                float* __restrict__ out) {
  extern __shared__ u16 sm[];
  u16* Xb = sm;                       // 64*264 = 16896 u16
  u16* Ao = sm + 16896;               // 64*264 = 16896 u16  (total 67584 B)

  const int b    = blockIdx.x;
  const int tid  = threadIdx.x;
  const int w    = tid >> 6;          // wave = head
  const int lane = tid & 63;
  const int g    = lane >> 4;
  const int li   = lane & 15;
  const int hc   = 32 * w;

  // ---- stage x -> bf16 LDS ----
  {
    const float4* xg = (const float4*)(x + (size_t)b * 16384);
    #pragma unroll
    for (int i = 0; i < 8; ++i) {
      int idx = tid + i * 512;
      float4 v = xg[idx];
      int n = idx >> 6, c = (idx & 63) * 4;
      u16x4 h;
      h[0] = bfbits(v.x); h[1] = bfbits(v.y); h[2] = bfbits(v.z); h[3] = bfbits(v.w);
      *(u16x4*)(Xb + n * 264 + c) = h;
    }
  }
  __syncthreads();

  const int xoff = li * 264 + 8 * g;        // per-lane Xb fragment base
  const float scale = 0.17677669529663687f; // 1/sqrt(32)

  // ======== Q sweep: Q^T = Wq . x^T -> qf fragments (B-operand of S-mfma) ========
  bf16x8 qf[4];
  {
    f32x4 aq[2][4];
    #pragma unroll
    for (int mt = 0; mt < 2; ++mt)
      #pragma unroll
      for (int nt = 0; nt < 4; ++nt) aq[mt][nt] = f32x4{0,0,0,0};
    #pragma unroll 2
    for (int ks = 0; ks < 8; ++ks) {
      bf16x8 xb[4];
      #pragma unroll
      for (int nt = 0; nt < 4; ++nt)
        xb[nt] = *(const bf16x8*)(Xb + xoff + nt * (16 * 264) + 32 * ks);
      #pragma unroll
      for (int mt = 0; mt < 2; ++mt) {
        bf16x8 wf = *(const bf16x8*)(wq + (hc + 16 * mt + li) * 256 + 32 * ks + 8 * g);
        #pragma unroll
        for (int nt = 0; nt < 4; ++nt)
          aq[mt][nt] = __builtin_amdgcn_mfma_f32_16x16x32_bf16(wf, xb[nt], aq[mt][nt], 0, 0, 0);
      }
    }
    #pragma unroll
    for (int j = 0; j < 8; ++j) {
      int d = (j < 4) ? (4 * g + j) : (16 + 4 * g + (j - 4));
      float bb = bq[hc + d];
      #pragma unroll
      for (int t = 0; t < 4; ++t)
        qf[t][j] = (__bf16)(((j < 4 ? aq[0][t][j] : aq[1][t][j - 4]) + bb) * scale);
    }
  }
  __builtin_amdgcn_sched_barrier(0);

  // ======== K sweep: K^T = Wk . x^T -> kf fragments (A-operand of S-mfma) ========
  bf16x8 kf[4];
  {
    f32x4 ak[2][4];
    #pragma unroll
    for (int mt = 0; mt < 2; ++mt)
      #pragma unroll
      for (int nt = 0; nt < 4; ++nt) ak[mt][nt] = f32x4{0,0,0,0};
    #pragma unroll 2
    for (int ks = 0; ks < 8; ++ks) {
      bf16x8 xb[4];
      #pragma unroll
      for (int nt = 0; nt < 4; ++nt)
        xb[nt] = *(const bf16x8*)(Xb + xoff + nt * (16 * 264) + 32 * ks);
      #pragma unroll
      for (int mt = 0; mt < 2; ++mt) {
        bf16x8 wf = *(const bf16x8*)(wq + (256 + hc + 16 * mt + li) * 256 + 32 * ks + 8 * g);
        #pragma unroll
        for (int nt = 0; nt < 4; ++nt)
          ak[mt][nt] = __builtin_amdgcn_mfma_f32_16x16x32_bf16(wf, xb[nt], ak[mt][nt], 0, 0, 0);
      }
    }
    #pragma unroll
    for (int j = 0; j < 8; ++j) {
      int d = (j < 4) ? (4 * g + j) : (16 + 4 * g + (j - 4));
      float bb = bq[256 + hc + d];
      #pragma unroll
      for (int t = 0; t < 4; ++t)
        kf[t][j] = (__bf16)((j < 4 ? ak[0][t][j] : ak[1][t][j - 4]) + bb);
    }
  }
  __builtin_amdgcn_sched_barrier(0);

  // ======== V sweep (non-transposed): V = x . Wv^T -> vb fragments (B-operand of PV) ========
  // av[mt][nt]: C row = token 16mt+4g+e, col = d = 16nt+li
  bf16x8 vb[2][2];
  {
    f32x4 av[4][2];
    #pragma unroll
    for (int mt = 0; mt < 4; ++mt)
      #pragma unroll
      for (int nt = 0; nt < 2; ++nt) av[mt][nt] = f32x4{0,0,0,0};
    #pragma unroll 2
    for (int ks = 0; ks < 8; ++ks) {
      bf16x8 xb[4];
      #pragma unroll
      for (int mt = 0; mt < 4; ++mt)
        xb[mt] = *(const bf16x8*)(Xb + xoff + mt * (16 * 264) + 32 * ks);
      #pragma unroll
      for (int nt = 0; nt < 2; ++nt) {
        bf16x8 wf = *(const bf16x8*)(wq + (512 + hc + 16 * nt + li) * 256 + 32 * ks + 8 * g);
        #pragma unroll
        for (int mt = 0; mt < 4; ++mt)
          av[mt][nt] = __builtin_amdgcn_mfma_f32_16x16x32_bf16(xb[mt], wf, av[mt][nt], 0, 0, 0);
      }
    }
    // C-frag -> PV B-frag via pi: vb[kk][nt][j] = V[token 32kk+pi(g,j)][d 16nt+li]
    #pragma unroll
    for (int nt = 0; nt < 2; ++nt) {
      float bb = bq[512 + hc + 16 * nt + li];
      #pragma unroll
      for (int kk = 0; kk < 2; ++kk)
        #pragma unroll
        for (int j = 0; j < 8; ++j)
          vb[kk][nt][j] = (__bf16)((j < 4 ? av[2 * kk][nt][j] : av[2 * kk + 1][nt][j - 4]) + bb);
    }
  }
  __builtin_amdgcn_sched_barrier(0);

  // ======== S^T = K.Q^T per query-tile; bias + softmax over keys; P fragments ========
  bf16x8 pa[4][2];
  {
    const float* bh = bias + w * 4096;      // [query][key]
    #pragma unroll
    for (int ct = 0; ct < 4; ++ct) {
      f32x4 s4[4];
      #pragma unroll
      for (int rt = 0; rt < 4; ++rt)
        s4[rt] = __builtin_amdgcn_mfma_f32_16x16x32_bf16(kf[rt], qf[ct], f32x4{0,0,0,0}, 0, 0, 0);
      const float* bq_row = bh + (16 * ct + li) * 64 + 4 * g;
      float mx = -1e30f;
      #pragma unroll
      for (int rt = 0; rt < 4; ++rt) {
        f32x4 bv = *(const f32x4*)(bq_row + 16 * rt);
        #pragma unroll
        for (int e = 0; e < 4; ++e) {
          s4[rt][e] += bv[e];
          mx = fmaxf(mx, s4[rt][e]);
        }
      }
      mx = fmaxf(mx, __shfl_xor(mx, 16));
      mx = fmaxf(mx, __shfl_xor(mx, 32));
      float sum = 0.f;
      #pragma unroll
      for (int rt = 0; rt < 4; ++rt)
        #pragma unroll
        for (int e = 0; e < 4; ++e) {
          float p = __expf(s4[rt][e] - mx);
          s4[rt][e] = p;
          sum += p;
        }
      sum += __shfl_xor(sum, 16);
      sum += __shfl_xor(sum, 32);
      float rs = 1.0f / sum;
      #pragma unroll
      for (int kk = 0; kk < 2; ++kk)
        #pragma unroll
        for (int j = 0; j < 8; ++j)
          pa[ct][kk][j] = (__bf16)((j < 4 ? s4[2 * kk][j] : s4[2 * kk + 1][j - 4]) * rs);
    }
  }
  __builtin_amdgcn_sched_barrier(0);

  // ======== O = P.V entirely in-register ========
  f32x4 o[4][2];
  #pragma unroll
  for (int mt = 0; mt < 4; ++mt)
    #pragma unroll
    for (int nt = 0; nt < 2; ++nt) o[mt][nt] = f32x4{0,0,0,0};
  #pragma unroll
  for (int kk = 0; kk < 2; ++kk)
    #pragma unroll
    for (int mt = 0; mt < 4; ++mt)
      #pragma unroll
      for (int nt = 0; nt < 2; ++nt)
        o[mt][nt] = __builtin_amdgcn_mfma_f32_16x16x32_bf16(pa[mt][kk], vb[kk][nt], o[mt][nt], 0, 0, 0);

  // ======== attn_out -> Ao (separate region; no aliasing with Xb) ========
  #pragma unroll
  for (int mt = 0; mt < 4; ++mt)
    #pragma unroll
    for (int nt = 0; nt < 2; ++nt)
      #pragma unroll
      for (int e = 0; e < 4; ++e)
        Ao[(16 * mt + 4 * g + e) * 264 + hc + 16 * nt + li] = bfbits(o[mt][nt][e]);
  __syncthreads();

  // ======== proj: out = attn_out @ Wp^T + bp ; wave w -> cols 32w..32w+31 ========
  f32x4 c2[4][2];
  #pragma unroll
  for (int rt = 0; rt < 4; ++rt)
    #pragma unroll
    for (int ct = 0; ct < 2; ++ct) c2[rt][ct] = f32x4{0,0,0,0};
  #pragma unroll 2
  for (int ks = 0; ks < 8; ++ks) {
    bf16x8 af[4];
    #pragma unroll
    for (int rt = 0; rt < 4; ++rt)
      af[rt] = *(const bf16x8*)(Ao + xoff + rt * (16 * 264) + 32 * ks);
    bf16x8 wf[2];
    #pragma unroll
    for (int ct = 0; ct < 2; ++ct)
      wf[ct] = *(const bf16x8*)(wp + (32 * w + 16 * ct + li) * 256 + 32 * ks + 8 * g);
    #pragma unroll
    for (int rt = 0; rt < 4; ++rt)
      #pragma unroll
      for (int ct = 0; ct < 2; ++ct)
        c2[rt][ct] = __builtin_amdgcn_mfma_f32_16x16x32_bf16(af[rt], wf[ct], c2[rt][ct], 0, 0, 0);
  }
  {
    float* og = out + (size_t)b * 16384;
    #pragma unroll
    for (int ct = 0; ct < 2; ++ct) {
      int col = 32 * w + 16 * ct + li;
      float bpv = bp[col];
      #pragma unroll
      for (int rt = 0; rt < 4; ++rt)
        #pragma unroll
        for (int e = 0; e < 4; ++e)
          og[(16 * rt + 4 * g + e) * 256 + col] = c2[rt][ct][e] + bpv;
    }
  }
}

extern "C" void kernel_launch(void* const* d_in, const int* in_sizes, int n_in,
                              void* d_out, int out_size, void* d_ws, size_t ws_size,
                              hipStream_t stream) {
  const float* x   = (const float*)d_in[0];
  const float* wqv = (const float*)d_in[1];
  const float* bq  = (const float*)d_in[2];
  const float* wpr = (const float*)d_in[3];
  const float* bp  = (const float*)d_in[4];
  const float* rpb = (const float*)d_in[5];
  const int*   rpi = (const int*)d_in[6];
  float* out = (float*)d_out;

  u16*   wqb   = (u16*)d_ws;            // 196608 bf16
  u16*   wpb   = wqb + 196608;          // 65536 bf16
  float* biasb = (float*)(wpb + 65536); // 32768 f32 ([h][query][key])

  wattn_prep<<<384, 512, 0, stream>>>(wqv, wpr, rpb, rpi, wqb, wpb, biasb);

  const size_t smem = (16896 + 16896) * sizeof(u16);  // 67584 B
  hipFuncSetAttribute(reinterpret_cast<const void*>(wattn_main),
                      hipFuncAttributeMaxDynamicSharedMemorySize, (int)smem);
  wattn_main<<<8192, 512, smem, stream>>>(x, wqb, bq, wpb, bp, biasb, out);
}

// Round 7
// 741.294 us; speedup vs baseline: 1.5711x; 1.0255x over previous
//
#include <hip/hip_runtime.h>
#include <hip/hip_bf16.h>

typedef __bf16 bf16x8 __attribute__((ext_vector_type(8)));
typedef float f32x4 __attribute__((ext_vector_type(4)));
typedef unsigned short u16;
typedef u16 u16x4 __attribute__((ext_vector_type(4)));

__device__ __forceinline__ u16 bfbits(float f) {
  return __builtin_bit_cast(u16, (__bf16)f);
}

// ---------------- prep: weights -> bf16, bias gather [h][query][key] ----------------
__global__ void wattn_prep(const float* __restrict__ wq, const float* __restrict__ wp,
                           const float* __restrict__ rpb, const int* __restrict__ rpi,
                           u16* __restrict__ wqb, u16* __restrict__ wpb,
                           float* __restrict__ biasb) {
  int i = blockIdx.x * blockDim.x + threadIdx.x;      // 196608 threads
  if (i < 196608) wqb[i] = bfbits(wq[i]);             // w_qkv [768][256]
  if (i < 65536)  wpb[i] = bfbits(wp[i]);             // w_proj [256][256]
  if (i < 32768) {                                    // bias [8][query 64][key 64]
    int h = i >> 12, nm = i & 4095;
    biasb[i] = rpb[rpi[nm] * 8 + h];
  }
}

// ---------------- fused window attention ----------------
// block = 1 window, 512 threads = 8 waves, wave w = head w
// LDS: Xb [64][264] bf16 | Ao [64][264] bf16 (separate; aliasing raced in R5).
// Q, K, V, P all in registers via the k-slot permutation
// pi(g,j) = j<4 ? 4g+j : 16+4g+(j-4).
// Phase order chosen to cap live registers (~110 peak, spill-free at cap 128):
//   Qsweep -> Ksweep -> S(all) -> softmax (qf,kf dead) -> Vsweep -> PV -> Ao -> proj
__global__ __launch_bounds__(512, 4)
void wattn_main(const float* __restrict__ x,
                const u16* __restrict__ wq, const float* __restrict__ bq,
                const u16* __restrict__ wp, const float* __restrict__ bp,
                const float* __restrict__ bias,
                float* __restrict__ out) {
  extern __shared__ u16 sm[];
  u16* Xb = sm;                       // 64*264 = 16896 u16
  u16* Ao = sm + 16896;               // 64*264 = 16896 u16  (total 67584 B)

  const int b    = blockIdx.x;
  const int tid  = threadIdx.x;
  const int w    = tid >> 6;          // wave = head
  const int lane = tid & 63;
  const int g    = lane >> 4;
  const int li   = lane & 15;
  const int hc   = 32 * w;

  // ---- stage x -> bf16 LDS ----
  {
    const float4* xg = (const float4*)(x + (size_t)b * 16384);
    #pragma unroll
    for (int i = 0; i < 8; ++i) {
      int idx = tid + i * 512;
      float4 v = xg[idx];
      int n = idx >> 6, c = (idx & 63) * 4;
      u16x4 h;
      h[0] = bfbits(v.x); h[1] = bfbits(v.y); h[2] = bfbits(v.z); h[3] = bfbits(v.w);
      *(u16x4*)(Xb + n * 264 + c) = h;
    }
  }
  __syncthreads();

  const int xoff = li * 264 + 8 * g;        // per-lane Xb fragment base
  const float scale = 0.17677669529663687f; // 1/sqrt(32)

  // ======== Q sweep: Q^T = Wq . x^T -> qf fragments (B-operand of S-mfma) ========
  bf16x8 qf[4];
  {
    f32x4 aq[2][4];
    #pragma unroll
    for (int mt = 0; mt < 2; ++mt)
      #pragma unroll
      for (int nt = 0; nt < 4; ++nt) aq[mt][nt] = f32x4{0,0,0,0};
    #pragma unroll 2
    for (int ks = 0; ks < 8; ++ks) {
      bf16x8 xb[4];
      #pragma unroll
      for (int nt = 0; nt < 4; ++nt)
        xb[nt] = *(const bf16x8*)(Xb + xoff + nt * (16 * 264) + 32 * ks);
      #pragma unroll
      for (int mt = 0; mt < 2; ++mt) {
        bf16x8 wf = *(const bf16x8*)(wq + (hc + 16 * mt + li) * 256 + 32 * ks + 8 * g);
        #pragma unroll
        for (int nt = 0; nt < 4; ++nt)
          aq[mt][nt] = __builtin_amdgcn_mfma_f32_16x16x32_bf16(wf, xb[nt], aq[mt][nt], 0, 0, 0);
      }
    }
    #pragma unroll
    for (int j = 0; j < 8; ++j) {
      int d = (j < 4) ? (4 * g + j) : (16 + 4 * g + (j - 4));
      float bb = bq[hc + d];
      #pragma unroll
      for (int t = 0; t < 4; ++t)
        qf[t][j] = (__bf16)(((j < 4 ? aq[0][t][j] : aq[1][t][j - 4]) + bb) * scale);
    }
  }
  __builtin_amdgcn_sched_barrier(0);

  // ======== K sweep: K^T = Wk . x^T -> kf fragments (A-operand of S-mfma) ========
  bf16x8 kf[4];
  {
    f32x4 ak[2][4];
    #pragma unroll
    for (int mt = 0; mt < 2; ++mt)
      #pragma unroll
      for (int nt = 0; nt < 4; ++nt) ak[mt][nt] = f32x4{0,0,0,0};
    #pragma unroll 2
    for (int ks = 0; ks < 8; ++ks) {
      bf16x8 xb[4];
      #pragma unroll
      for (int nt = 0; nt < 4; ++nt)
        xb[nt] = *(const bf16x8*)(Xb + xoff + nt * (16 * 264) + 32 * ks);
      #pragma unroll
      for (int mt = 0; mt < 2; ++mt) {
        bf16x8 wf = *(const bf16x8*)(wq + (256 + hc + 16 * mt + li) * 256 + 32 * ks + 8 * g);
        #pragma unroll
        for (int nt = 0; nt < 4; ++nt)
          ak[mt][nt] = __builtin_amdgcn_mfma_f32_16x16x32_bf16(wf, xb[nt], ak[mt][nt], 0, 0, 0);
      }
    }
    #pragma unroll
    for (int j = 0; j < 8; ++j) {
      int d = (j < 4) ? (4 * g + j) : (16 + 4 * g + (j - 4));
      float bb = bq[256 + hc + d];
      #pragma unroll
      for (int t = 0; t < 4; ++t)
        kf[t][j] = (__bf16)((j < 4 ? ak[0][t][j] : ak[1][t][j - 4]) + bb);
    }
  }
  __builtin_amdgcn_sched_barrier(0);

  // ======== S^T = K.Q^T (all 16 tiles; qf,kf die after this) ========
  f32x4 s[4][4];
  #pragma unroll
  for (int ct = 0; ct < 4; ++ct)
    #pragma unroll
    for (int rt = 0; rt < 4; ++rt)
      s[rt][ct] = __builtin_amdgcn_mfma_f32_16x16x32_bf16(kf[rt], qf[ct], f32x4{0,0,0,0}, 0, 0, 0);
  __builtin_amdgcn_sched_barrier(0);

  // ======== bias + softmax over keys; P fragments (s dies per-ct) ========
  bf16x8 pa[4][2];
  {
    const float* bh = bias + w * 4096;      // [query][key]
    #pragma unroll
    for (int ct = 0; ct < 4; ++ct) {
      const float* bq_row = bh + (16 * ct + li) * 64 + 4 * g;
      float mx = -1e30f;
      #pragma unroll
      for (int rt = 0; rt < 4; ++rt) {
        f32x4 bv = *(const f32x4*)(bq_row + 16 * rt);
        #pragma unroll
        for (int e = 0; e < 4; ++e) {
          s[rt][ct][e] += bv[e];
          mx = fmaxf(mx, s[rt][ct][e]);
        }
      }
      mx = fmaxf(mx, __shfl_xor(mx, 16));
      mx = fmaxf(mx, __shfl_xor(mx, 32));
      float sum = 0.f;
      #pragma unroll
      for (int rt = 0; rt < 4; ++rt)
        #pragma unroll
        for (int e = 0; e < 4; ++e) {
          float p = __expf(s[rt][ct][e] - mx);
          s[rt][ct][e] = p;
          sum += p;
        }
      sum += __shfl_xor(sum, 16);
      sum += __shfl_xor(sum, 32);
      float rs = 1.0f / sum;
      #pragma unroll
      for (int kk = 0; kk < 2; ++kk)
        #pragma unroll
        for (int j = 0; j < 8; ++j)
          pa[ct][kk][j] = (__bf16)((j < 4 ? s[2 * kk][ct][j] : s[2 * kk + 1][ct][j - 4]) * rs);
    }
  }
  __builtin_amdgcn_sched_barrier(0);

  // ======== V sweep (after softmax; only pa persists): V = x . Wv^T ========
  bf16x8 vb[2][2];
  {
    f32x4 av[4][2];
    #pragma unroll
    for (int mt = 0; mt < 4; ++mt)
      #pragma unroll
      for (int nt = 0; nt < 2; ++nt) av[mt][nt] = f32x4{0,0,0,0};
    #pragma unroll 2
    for (int ks = 0; ks < 8; ++ks) {
      bf16x8 xb[4];
      #pragma unroll
      for (int mt = 0; mt < 4; ++mt)
        xb[mt] = *(const bf16x8*)(Xb + xoff + mt * (16 * 264) + 32 * ks);
      #pragma unroll
      for (int nt = 0; nt < 2; ++nt) {
        bf16x8 wf = *(const bf16x8*)(wq + (512 + hc + 16 * nt + li) * 256 + 32 * ks + 8 * g);
        #pragma unroll
        for (int mt = 0; mt < 4; ++mt)
          av[mt][nt] = __builtin_amdgcn_mfma_f32_16x16x32_bf16(xb[mt], wf, av[mt][nt], 0, 0, 0);
      }
    }
    // C-frag -> PV B-frag via pi: vb[kk][nt][j] = V[token 32kk+pi(g,j)][d 16nt+li]
    #pragma unroll
    for (int nt = 0; nt < 2; ++nt) {
      float bb = bq[512 + hc + 16 * nt + li];
      #pragma unroll
      for (int kk = 0; kk < 2; ++kk)
        #pragma unroll
        for (int j = 0; j < 8; ++j)
          vb[kk][nt][j] = (__bf16)((j < 4 ? av[2 * kk][nt][j] : av[2 * kk + 1][nt][j - 4]) + bb);
    }
  }
  __builtin_amdgcn_sched_barrier(0);

  // ======== O = P.V entirely in-register ========
  f32x4 o[4][2];
  #pragma unroll
  for (int mt = 0; mt < 4; ++mt)
    #pragma unroll
    for (int nt = 0; nt < 2; ++nt) o[mt][nt] = f32x4{0,0,0,0};
  #pragma unroll
  for (int kk = 0; kk < 2; ++kk)
    #pragma unroll
    for (int mt = 0; mt < 4; ++mt)
      #pragma unroll
      for (int nt = 0; nt < 2; ++nt)
        o[mt][nt] = __builtin_amdgcn_mfma_f32_16x16x32_bf16(pa[mt][kk], vb[kk][nt], o[mt][nt], 0, 0, 0);

  // ======== attn_out -> Ao (separate region; no aliasing with Xb) ========
  #pragma unroll
  for (int mt = 0; mt < 4; ++mt)
    #pragma unroll
    for (int nt = 0; nt < 2; ++nt)
      #pragma unroll
      for (int e = 0; e < 4; ++e)
        Ao[(16 * mt + 4 * g + e) * 264 + hc + 16 * nt + li] = bfbits(o[mt][nt][e]);
  __syncthreads();

  // ======== proj: out = attn_out @ Wp^T + bp ; wave w -> cols 32w..32w+31 ========
  f32x4 c2[4][2];
  #pragma unroll
  for (int rt = 0; rt < 4; ++rt)
    #pragma unroll
    for (int ct = 0; ct < 2; ++ct) c2[rt][ct] = f32x4{0,0,0,0};
  #pragma unroll 2
  for (int ks = 0; ks < 8; ++ks) {
    bf16x8 af[4];
    #pragma unroll
    for (int rt = 0; rt < 4; ++rt)
      af[rt] = *(const bf16x8*)(Ao + xoff + rt * (16 * 264) + 32 * ks);
    bf16x8 wf[2];
    #pragma unroll
    for (int ct = 0; ct < 2; ++ct)
      wf[ct] = *(const bf16x8*)(wp + (32 * w + 16 * ct + li) * 256 + 32 * ks + 8 * g);
    #pragma unroll
    for (int rt = 0; rt < 4; ++rt)
      #pragma unroll
      for (int ct = 0; ct < 2; ++ct)
        c2[rt][ct] = __builtin_amdgcn_mfma_f32_16x16x32_bf16(af[rt], wf[ct], c2[rt][ct], 0, 0, 0);
  }
  {
    float* og = out + (size_t)b * 16384;
    #pragma unroll
    for (int ct = 0; ct < 2; ++ct) {
      int col = 32 * w + 16 * ct + li;
      float bpv = bp[col];
      #pragma unroll
      for (int rt = 0; rt < 4; ++rt)
        #pragma unroll
        for (int e = 0; e < 4; ++e)
          og[(16 * rt + 4 * g + e) * 256 + col] = c2[rt][ct][e] + bpv;
    }
  }
}

extern "C" void kernel_launch(void* const* d_in, const int* in_sizes, int n_in,
                              void* d_out, int out_size, void* d_ws, size_t ws_size,
                              hipStream_t stream) {
  const float* x   = (const float*)d_in[0];
  const float* wqv = (const float*)d_in[1];
  const float* bq  = (const float*)d_in[2];
  const float* wpr = (const float*)d_in[3];
  const float* bp  = (const float*)d_in[4];
  const float* rpb = (const float*)d_in[5];
  const int*   rpi = (const int*)d_in[6];
  float* out = (float*)d_out;

  u16*   wqb   = (u16*)d_ws;            // 196608 bf16
  u16*   wpb   = wqb + 196608;          // 65536 bf16
  float* biasb = (float*)(wpb + 65536); // 32768 f32 ([h][query][key])

  wattn_prep<<<384, 512, 0, stream>>>(wqv, wpr, rpb, rpi, wqb, wpb, biasb);

  const size_t smem = (16896 + 16896) * sizeof(u16);  // 67584 B
  hipFuncSetAttribute(reinterpret_cast<const void*>(wattn_main),
                      hipFuncAttributeMaxDynamicSharedMemorySize, (int)smem);
  wattn_main<<<8192, 512, smem, stream>>>(x, wqb, bq, wpb, bp, biasb, out);
}

// Round 8
// 735.691 us; speedup vs baseline: 1.5831x; 1.0076x over previous
//
#include <hip/hip_runtime.h>
#include <hip/hip_bf16.h>

typedef __bf16 bf16x8 __attribute__((ext_vector_type(8)));
typedef float f32x4 __attribute__((ext_vector_type(4)));
typedef unsigned short u16;
typedef u16 u16x4 __attribute__((ext_vector_type(4)));

__device__ __forceinline__ u16 bfbits(float f) {
  return __builtin_bit_cast(u16, (__bf16)f);
}

// ---------------- prep: weights -> bf16, bias gather [h][query][key] ----------------
__global__ void wattn_prep(const float* __restrict__ wq, const float* __restrict__ wp,
                           const float* __restrict__ rpb, const int* __restrict__ rpi,
                           u16* __restrict__ wqb, u16* __restrict__ wpb,
                           float* __restrict__ biasb) {
  int i = blockIdx.x * blockDim.x + threadIdx.x;      // 196608 threads
  if (i < 196608) wqb[i] = bfbits(wq[i]);             // w_qkv [768][256]
  if (i < 65536)  wpb[i] = bfbits(wp[i]);             // w_proj [256][256]
  if (i < 32768) {                                    // bias [8][query 64][key 64]
    int h = i >> 12, nm = i & 4095;
    biasb[i] = rpb[rpi[nm] * 8 + h];
  }
}

// ---------------- fused window attention ----------------
// block = 1 window, 512 threads = 8 waves, wave w = head w
// LDS: Xb [64 rows][528 B] XOR-swizzled | Ao [64][528 B] XOR-swizzled (separate regions).
// Swizzle: byte_col ^= (row&7)<<4 on both write and read (involution, 16B-window safe).
// Q,K,V,P in registers via k-slot permutation pi(g,j) = j<4 ? 4g+j : 16+4g+(j-4).
// Bias folded into MFMA C-input for Q,K,V,S,proj.
// Phase order (register ceiling ~110 < cap 128):
//   stage -> fused Q+K sweep -> S+softmax (per-ct) -> V sweep -> PV -> Ao -> proj
__global__ __launch_bounds__(512, 4)
void wattn_main(const float* __restrict__ x,
                const u16* __restrict__ wq, const float* __restrict__ bq,
                const u16* __restrict__ wp, const float* __restrict__ bp,
                const float* __restrict__ bias,
                float* __restrict__ out) {
  extern __shared__ char smc[];
  char* Xb = smc;                     // 64*528 = 33792 B
  char* Ao = smc + 33792;             // 64*528 = 33792 B (total 67584 B)

  const int b    = blockIdx.x;
  const int tid  = threadIdx.x;
  const int w    = tid >> 6;          // wave = head
  const int lane = tid & 63;
  const int g    = lane >> 4;
  const int li   = lane & 15;
  const int hc   = 32 * w;

  // ---- stage x -> bf16 LDS (swizzled) ----
  {
    const float4* xg = (const float4*)(x + (size_t)b * 16384);
    #pragma unroll
    for (int i = 0; i < 8; ++i) {
      int idx = tid + i * 512;
      float4 v = xg[idx];
      int n = idx >> 6, cb = (idx & 63) << 3;     // byte col (8B chunks)
      u16x4 h;
      h[0] = bfbits(v.x); h[1] = bfbits(v.y); h[2] = bfbits(v.z); h[3] = bfbits(v.w);
      *(u16x4*)(Xb + n * 528 + (cb ^ ((n & 7) << 4))) = h;
    }
  }
  __syncthreads();

  const int swz = (li & 7) << 4;
  const char* Xrow = Xb + li * 528;           // A/B-frag rows: row = li + 16*t
  const float scale = 0.17677669529663687f;   // 1/sqrt(32)

  // ======== fused Q+K sweep: Q^T|K^T = Wq|Wk . x^T (bias via C-init) ========
  bf16x8 qf[4], kf[4];
  {
    f32x4 aq[2][4], ak[2][4];
    #pragma unroll
    for (int mt = 0; mt < 2; ++mt) {
      f32x4 bqv = *(const f32x4*)(bq + hc + 16 * mt + 4 * g);
      f32x4 bkv = *(const f32x4*)(bq + 256 + hc + 16 * mt + 4 * g);
      #pragma unroll
      for (int nt = 0; nt < 4; ++nt) { aq[mt][nt] = bqv; ak[mt][nt] = bkv; }
    }
    #pragma unroll 2
    for (int ks = 0; ks < 8; ++ks) {
      bf16x8 xb[4];
      #pragma unroll
      for (int nt = 0; nt < 4; ++nt)
        xb[nt] = *(const bf16x8*)(Xrow + nt * (16 * 528) + ((64 * ks + 16 * g) ^ swz));
      #pragma unroll
      for (int mt = 0; mt < 2; ++mt) {
        bf16x8 wfq = *(const bf16x8*)(wq + (hc + 16 * mt + li) * 256 + 32 * ks + 8 * g);
        #pragma unroll
        for (int nt = 0; nt < 4; ++nt)
          aq[mt][nt] = __builtin_amdgcn_mfma_f32_16x16x32_bf16(wfq, xb[nt], aq[mt][nt], 0, 0, 0);
        bf16x8 wfk = *(const bf16x8*)(wq + (256 + hc + 16 * mt + li) * 256 + 32 * ks + 8 * g);
        #pragma unroll
        for (int nt = 0; nt < 4; ++nt)
          ak[mt][nt] = __builtin_amdgcn_mfma_f32_16x16x32_bf16(wfk, xb[nt], ak[mt][nt], 0, 0, 0);
      }
    }
    // C-frag -> S-operand frags via pi (bias already in; Q scaled here)
    #pragma unroll
    for (int j = 0; j < 8; ++j)
      #pragma unroll
      for (int t = 0; t < 4; ++t) {
        qf[t][j] = (__bf16)((j < 4 ? aq[0][t][j] : aq[1][t][j - 4]) * scale);
        kf[t][j] = (__bf16)((j < 4 ? ak[0][t][j] : ak[1][t][j - 4]));
      }
  }
  __builtin_amdgcn_sched_barrier(0);

  // ======== S^T = K.Q^T + bias (C-init) per query-tile; softmax; P frags ========
  bf16x8 pa[4][2];
  {
    const float* bh = bias + w * 4096;      // [query][key]
    #pragma unroll
    for (int ct = 0; ct < 4; ++ct) {
      const float* br = bh + (16 * ct + li) * 64 + 4 * g;
      f32x4 s4[4];
      #pragma unroll
      for (int rt = 0; rt < 4; ++rt)
        s4[rt] = __builtin_amdgcn_mfma_f32_16x16x32_bf16(kf[rt], qf[ct],
                                                         *(const f32x4*)(br + 16 * rt), 0, 0, 0);
      float mx = -1e30f;
      #pragma unroll
      for (int rt = 0; rt < 4; ++rt)
        #pragma unroll
        for (int e = 0; e < 4; ++e) mx = fmaxf(mx, s4[rt][e]);
      mx = fmaxf(mx, __shfl_xor(mx, 16));
      mx = fmaxf(mx, __shfl_xor(mx, 32));
      float sum = 0.f;
      #pragma unroll
      for (int rt = 0; rt < 4; ++rt)
        #pragma unroll
        for (int e = 0; e < 4; ++e) {
          float p = __expf(s4[rt][e] - mx);
          s4[rt][e] = p;
          sum += p;
        }
      sum += __shfl_xor(sum, 16);
      sum += __shfl_xor(sum, 32);
      float rs = 1.0f / sum;
      #pragma unroll
      for (int kk = 0; kk < 2; ++kk)
        #pragma unroll
        for (int j = 0; j < 8; ++j)
          pa[ct][kk][j] = (__bf16)((j < 4 ? s4[2 * kk][j] : s4[2 * kk + 1][j - 4]) * rs);
    }
  }
  __builtin_amdgcn_sched_barrier(0);

  // ======== V sweep (only pa persists): V = x . Wv^T (bias via C-init) ========
  bf16x8 vb[2][2];
  {
    f32x4 av[4][2];
    #pragma unroll
    for (int nt = 0; nt < 2; ++nt) {
      float bb = bq[512 + hc + 16 * nt + li];
      #pragma unroll
      for (int mt = 0; mt < 4; ++mt) av[mt][nt] = f32x4{bb, bb, bb, bb};
    }
    #pragma unroll 2
    for (int ks = 0; ks < 8; ++ks) {
      bf16x8 xbv[4];
      #pragma unroll
      for (int mt = 0; mt < 4; ++mt)
        xbv[mt] = *(const bf16x8*)(Xrow + mt * (16 * 528) + ((64 * ks + 16 * g) ^ swz));
      #pragma unroll
      for (int nt = 0; nt < 2; ++nt) {
        bf16x8 wf = *(const bf16x8*)(wq + (512 + hc + 16 * nt + li) * 256 + 32 * ks + 8 * g);
        #pragma unroll
        for (int mt = 0; mt < 4; ++mt)
          av[mt][nt] = __builtin_amdgcn_mfma_f32_16x16x32_bf16(xbv[mt], wf, av[mt][nt], 0, 0, 0);
      }
    }
    // C-frag -> PV B-frag via pi: vb[kk][nt][j] = V[token 32kk+pi(g,j)][d 16nt+li]
    #pragma unroll
    for (int nt = 0; nt < 2; ++nt)
      #pragma unroll
      for (int kk = 0; kk < 2; ++kk)
        #pragma unroll
        for (int j = 0; j < 8; ++j)
          vb[kk][nt][j] = (__bf16)((j < 4 ? av[2 * kk][nt][j] : av[2 * kk + 1][nt][j - 4]));
  }
  __builtin_amdgcn_sched_barrier(0);

  // ======== O = P.V entirely in-register ========
  f32x4 o[4][2];
  #pragma unroll
  for (int mt = 0; mt < 4; ++mt)
    #pragma unroll
    for (int nt = 0; nt < 2; ++nt) o[mt][nt] = f32x4{0, 0, 0, 0};
  #pragma unroll
  for (int kk = 0; kk < 2; ++kk)
    #pragma unroll
    for (int mt = 0; mt < 4; ++mt)
      #pragma unroll
      for (int nt = 0; nt < 2; ++nt)
        o[mt][nt] = __builtin_amdgcn_mfma_f32_16x16x32_bf16(pa[mt][kk], vb[kk][nt], o[mt][nt], 0, 0, 0);

  // ======== attn_out -> Ao (separate region, swizzled) ========
  #pragma unroll
  for (int mt = 0; mt < 4; ++mt)
    #pragma unroll
    for (int nt = 0; nt < 2; ++nt)
      #pragma unroll
      for (int e = 0; e < 4; ++e) {
        int row = 16 * mt + 4 * g + e;
        int cb = (hc + 16 * nt + li) * 2;
        *(u16*)(Ao + row * 528 + (cb ^ (((4 * g + e) & 7) << 4))) = bfbits(o[mt][nt][e]);
      }
  __syncthreads();

  // ======== proj: out = attn_out @ Wp^T + bp (C-init) ========
  f32x4 c2[4][2];
  #pragma unroll
  for (int ct = 0; ct < 2; ++ct) {
    float bb = bp[32 * w + 16 * ct + li];
    #pragma unroll
    for (int rt = 0; rt < 4; ++rt) c2[rt][ct] = f32x4{bb, bb, bb, bb};
  }
  {
    const char* Arow = Ao + li * 528;
    #pragma unroll 2
    for (int ks = 0; ks < 8; ++ks) {
      bf16x8 af[4];
      #pragma unroll
      for (int rt = 0; rt < 4; ++rt)
        af[rt] = *(const bf16x8*)(Arow + rt * (16 * 528) + ((64 * ks + 16 * g) ^ swz));
      bf16x8 wf[2];
      #pragma unroll
      for (int ct = 0; ct < 2; ++ct)
        wf[ct] = *(const bf16x8*)(wp + (32 * w + 16 * ct + li) * 256 + 32 * ks + 8 * g);
      #pragma unroll
      for (int rt = 0; rt < 4; ++rt)
        #pragma unroll
        for (int ct = 0; ct < 2; ++ct)
          c2[rt][ct] = __builtin_amdgcn_mfma_f32_16x16x32_bf16(af[rt], wf[ct], c2[rt][ct], 0, 0, 0);
    }
  }
  {
    float* og = out + (size_t)b * 16384;
    #pragma unroll
    for (int ct = 0; ct < 2; ++ct) {
      int col = 32 * w + 16 * ct + li;
      #pragma unroll
      for (int rt = 0; rt < 4; ++rt)
        #pragma unroll
        for (int e = 0; e < 4; ++e)
          og[(16 * rt + 4 * g + e) * 256 + col] = c2[rt][ct][e];
    }
  }
}

extern "C" void kernel_launch(void* const* d_in, const int* in_sizes, int n_in,
                              void* d_out, int out_size, void* d_ws, size_t ws_size,
                              hipStream_t stream) {
  const float* x   = (const float*)d_in[0];
  const float* wqv = (const float*)d_in[1];
  const float* bq  = (const float*)d_in[2];
  const float* wpr = (const float*)d_in[3];
  const float* bp  = (const float*)d_in[4];
  const float* rpb = (const float*)d_in[5];
  const int*   rpi = (const int*)d_in[6];
  float* out = (float*)d_out;

  u16*   wqb   = (u16*)d_ws;            // 196608 bf16
  u16*   wpb   = wqb + 196608;          // 65536 bf16
  float* biasb = (float*)(wpb + 65536); // 32768 f32 ([h][query][key])

  wattn_prep<<<384, 512, 0, stream>>>(wqv, wpr, rpb, rpi, wqb, wpb, biasb);

  const size_t smem = 67584;            // 2 x 64 x 528 B
  hipFuncSetAttribute(reinterpret_cast<const void*>(wattn_main),
                      hipFuncAttributeMaxDynamicSharedMemorySize, (int)smem);
  wattn_main<<<8192, 512, smem, stream>>>(x, wqb, bq, wpb, bp, biasb, out);
}